// Round 5
// baseline (81.018 us; speedup 1.0000x reference)
//
#include <hip/hip_runtime.h>

#define NT 256

typedef float f2 __attribute__((ext_vector_type(2)));

// ---------------- transpose x [32][1024] -> xT [1024][32] ----------------
__global__ __launch_bounds__(NT) void transp_x(const float* __restrict__ x,
                                               float* __restrict__ xT) {
  __shared__ float T[64][33];
  const int k0 = blockIdx.x * 64;
  const int t = threadIdx.x;
  {
    const int s = t * 8;           // 0..2047
    const int b = s >> 6;          // 0..31
    const int c = s & 63;          // 0,8,..,56
    float4 v0 = *(const float4*)&x[b * 1024 + k0 + c];
    float4 v1 = *(const float4*)&x[b * 1024 + k0 + c + 4];
    T[c + 0][b] = v0.x; T[c + 1][b] = v0.y; T[c + 2][b] = v0.z; T[c + 3][b] = v0.w;
    T[c + 4][b] = v1.x; T[c + 5][b] = v1.y; T[c + 6][b] = v1.z; T[c + 7][b] = v1.w;
  }
  __syncthreads();
  {
    const int s = t * 8;
    const int r = s >> 5;          // 0..63
    const int b0 = s & 31;         // 0,8,16,24
    float o[8];
    #pragma unroll
    for (int q = 0; q < 8; ++q) o[q] = T[r][b0 + q];
    *(float4*)&xT[(k0 + r) * 32 + b0]     = make_float4(o[0], o[1], o[2], o[3]);
    *(float4*)&xT[(k0 + r) * 32 + b0 + 4] = make_float4(o[4], o[5], o[6], o[7]);
  }
}

// ---------------- meta body ----------------
// nw[o,i] = mb2 + sum_j mw2[j]*relu(mw1[3j]*vin[i] + mw1[3j+1]*W[o,i] + mw1[3j+2]*vout[o] + mb1[j])
__device__ __forceinline__ void meta_body(
    int g,
    const float* __restrict__ w1, const float* __restrict__ w2, const float* __restrict__ w3,
    const float* __restrict__ a0, const float* __restrict__ a1, const float* __restrict__ a2,
    const float* __restrict__ a3,
    float* __restrict__ n1, float* __restrict__ n2, float* __restrict__ n3,
    const float* __restrict__ mw1, const float* __restrict__ mb1,
    const float* __restrict__ mw2, const float* __restrict__ mb2) {
  const int n1c = (2048 * 1024) / 8;
  const int n2c = (2048 * 2048) / 8;

  const float* W; const float* vin; const float* vout; float* nw;
  int sh, e;
  if (g < n1c)            { W = w1; vin = a0; vout = a1; nw = n1; sh = 10; e = g; }
  else if (g < n1c + n2c) { W = w2; vin = a1; vout = a2; nw = n2; sh = 11; e = g - n1c; }
  else                    { W = w3; vin = a2; vout = a3; nw = n3; sh = 11; e = g - n1c - n2c; }

  const int base = e << 3;
  const int o = base >> sh;
  const int i0 = base & ((1 << sh) - 1);

  f2 wv[4], vv[4];
  {
    float4 t0 = *reinterpret_cast<const float4*>(&W[base]);
    float4 t1 = *reinterpret_cast<const float4*>(&W[base + 4]);
    wv[0] = (f2){t0.x, t0.y}; wv[1] = (f2){t0.z, t0.w};
    wv[2] = (f2){t1.x, t1.y}; wv[3] = (f2){t1.z, t1.w};
    float4 u0 = *reinterpret_cast<const float4*>(&vin[i0]);
    float4 u1 = *reinterpret_cast<const float4*>(&vin[i0 + 4]);
    vv[0] = (f2){u0.x, u0.y}; vv[1] = (f2){u0.z, u0.w};
    vv[2] = (f2){u1.x, u1.y}; vv[3] = (f2){u1.z, u1.w};
  }
  const float vo = vout[o];
  const float c2 = mb2[0];

  float r[32];
  #pragma unroll
  for (int j = 0; j < 32; ++j)
    r[j] = fmaf(mw1[3 * j + 2], vo, mb1[j]);

  f2 acc[4];
  #pragma unroll
  for (int p = 0; p < 4; ++p) acc[p] = (f2){c2, c2};

  const f2 zero = (f2){0.f, 0.f};
  #pragma unroll
  for (int j = 0; j < 32; ++j) {
    const float aj = mw1[3 * j];
    const float bj = mw1[3 * j + 1];
    const float mj = mw2[j];
    const f2 a2v = (f2){aj, aj};
    const f2 b2v = (f2){bj, bj};
    const f2 m2v = (f2){mj, mj};
    const f2 r2v = (f2){r[j], r[j]};
    #pragma unroll
    for (int p = 0; p < 4; ++p) {
#if __has_builtin(__builtin_elementwise_fma) && __has_builtin(__builtin_elementwise_max)
      f2 q = __builtin_elementwise_fma(a2v, vv[p], r2v);
      f2 h = __builtin_elementwise_fma(b2v, wv[p], q);
      h = __builtin_elementwise_max(h, zero);
      acc[p] = __builtin_elementwise_fma(m2v, h, acc[p]);
#else
      f2 h;
      h.x = fmaxf(fmaf(bj, wv[p].x, fmaf(aj, vv[p].x, r[j])), 0.f);
      h.y = fmaxf(fmaf(bj, wv[p].y, fmaf(aj, vv[p].y, r[j])), 0.f);
      acc[p].x = fmaf(mj, h.x, acc[p].x);
      acc[p].y = fmaf(mj, h.y, acc[p].y);
#endif
    }
  }

  *reinterpret_cast<float4*>(&nw[base])     = make_float4(acc[0].x, acc[0].y, acc[1].x, acc[1].y);
  *reinterpret_cast<float4*>(&nw[base + 4]) = make_float4(acc[2].x, acc[2].y, acc[3].x, acc[3].y);
}

// ---------------- gemm body: LDS-free, A via scalar loads ----------------
// Thread owns one output column o, acc[32] over batch. Wave owns one k-slice.
// P[slice][o][b] = sum_{k in slice} AT[k][b] * W[o][k]
template<int KLW, int NTO_LOG>
__device__ __forceinline__ void gemm_body(
    int gbid, const float* __restrict__ AT, const float* __restrict__ W,
    float* __restrict__ P, int K, int O) {
  const int tid = threadIdx.x;
  const int otile = gbid & ((1 << NTO_LOG) - 1);   // nto % 8 == 0 -> XCD-stable
  const int ksx = gbid >> NTO_LOG;
  const int ol = tid & 63;
  const int o = (otile << 6) + ol;
  // wave-uniform slice index; readfirstlane so the compiler scalarizes A loads
  const int slice = __builtin_amdgcn_readfirstlane(ksx * 4 + (tid >> 6));
  const int kbeg = slice * KLW;

  const float* __restrict__ wp = W + (size_t)o * K + kbeg;
  const float* __restrict__ ap = AT + (size_t)kbeg * 32;

  float acc[32];
  #pragma unroll
  for (int b = 0; b < 32; ++b) acc[b] = 0.f;

  #pragma unroll 2
  for (int kk = 0; kk < KLW; kk += 4) {
    const float4 wv = *(const float4*)(wp + kk);
    #pragma unroll
    for (int q = 0; q < 4; ++q) {
      const float wq = (q == 0) ? wv.x : (q == 1) ? wv.y : (q == 2) ? wv.z : wv.w;
      #pragma unroll
      for (int b = 0; b < 32; ++b)
        acc[b] = fmaf(wq, ap[(kk + q) * 32 + b], acc[b]);
    }
  }

  float* pp = P + ((size_t)slice * O + o) * 32;
  #pragma unroll
  for (int c = 0; c < 8; ++c)
    *(float4*)(pp + c * 4) =
        make_float4(acc[c * 4], acc[c * 4 + 1], acc[c * 4 + 2], acc[c * 4 + 3]);
}

// ---------------- combo: gemm blocks + meta blocks (zero LDS) ----------------
template<int KLW, int NTO_LOG>
__global__ __launch_bounds__(NT) void gemm_meta(
    int nGemm,
    const float* __restrict__ AT, const float* __restrict__ W,
    float* __restrict__ P, int K, int O,
    int gbase,
    const float* __restrict__ w1, const float* __restrict__ w2, const float* __restrict__ w3,
    const float* __restrict__ a0, const float* __restrict__ a1, const float* __restrict__ a2,
    const float* __restrict__ a3,
    float* __restrict__ n1, float* __restrict__ n2, float* __restrict__ n3,
    const float* __restrict__ mw1, const float* __restrict__ mb1,
    const float* __restrict__ mw2, const float* __restrict__ mb2) {
  const int bid = blockIdx.x;
  if (bid < nGemm) {
    gemm_body<KLW, NTO_LOG>(bid, AT, W, P, K, O);
  } else {
    const int g = gbase + (bid - nGemm) * NT + threadIdx.x;
    meta_body(g, w1, w2, w3, a0, a1, a2, a3, n1, n2, n3, mw1, mb1, mw2, mb2);
  }
}

__global__ __launch_bounds__(NT) void meta_only(
    int gbase,
    const float* __restrict__ w1, const float* __restrict__ w2, const float* __restrict__ w3,
    const float* __restrict__ a0, const float* __restrict__ a1, const float* __restrict__ a2,
    const float* __restrict__ a3,
    float* __restrict__ n1, float* __restrict__ n2, float* __restrict__ n3,
    const float* __restrict__ mw1, const float* __restrict__ mb1,
    const float* __restrict__ mw2, const float* __restrict__ mb2) {
  const int g = gbase + blockIdx.x * NT + threadIdx.x;
  meta_body(g, w1, w2, w3, a0, a1, a2, a3, n1, n2, n3, mw1, mb1, mw2, mb2);
}

// ---------------- reduce: sum slices + bias + relu -> aT [O][32] + row0 ----------------
template<int NS, int NTO_LOG>
__global__ __launch_bounds__(NT) void reduceT(
    const float* __restrict__ P, const float* __restrict__ bias,
    float* __restrict__ aT, float* __restrict__ row0, int O) {
  const int otile = blockIdx.x & ((1 << NTO_LOG) - 1);
  const int part = blockIdx.x >> NTO_LOG;
  const int local = part * NT + threadIdx.x;        // 0..2047 within otile
  const int o = (otile << 6) + (local >> 5);
  const int b = local & 31;
  float s = 0.f;
  #pragma unroll
  for (int sl = 0; sl < NS; ++sl)
    s += P[((size_t)sl * O + o) * 32 + b];
  const float v = fmaxf(s + bias[o], 0.f);
  aT[o * 32 + b] = v;
  if (b == 0) row0[o] = v;
}

// ---------------- reduce for layer 3: output b-major into d_out ----------------
template<int NS>
__global__ __launch_bounds__(NT) void reduceOut(
    const float* __restrict__ P, const float* __restrict__ bias,
    float* __restrict__ out, int O) {
  __shared__ float T[8][33];
  const int otile = blockIdx.x & 15;
  const int part = blockIdx.x >> 4;
  const int local = part * NT + threadIdx.x;
  const int o = (otile << 6) + (local >> 5);
  const int b = local & 31;
  float s = 0.f;
  #pragma unroll
  for (int sl = 0; sl < NS; ++sl)
    s += P[((size_t)sl * O + o) * 32 + b];
  T[(local >> 5) & 7][b] = fmaxf(s + bias[o], 0.f);
  __syncthreads();
  const int b2 = threadIdx.x >> 3;    // 0..31
  const int oo = threadIdx.x & 7;     // 0..7
  out[b2 * O + (otile << 6) + (part << 3) + oo] = T[oo][b2];
}

extern "C" void kernel_launch(void* const* d_in, const int* in_sizes, int n_in,
                              void* d_out, int out_size, void* d_ws, size_t ws_size,
                              hipStream_t stream) {
  const float* x   = (const float*)d_in[0];
  const float* w1  = (const float*)d_in[1];
  const float* b1  = (const float*)d_in[2];
  const float* w2  = (const float*)d_in[3];
  const float* b2  = (const float*)d_in[4];
  const float* w3  = (const float*)d_in[5];
  const float* b3  = (const float*)d_in[6];
  const float* mw1 = (const float*)d_in[7];
  const float* mb1 = (const float*)d_in[8];
  const float* mw2 = (const float*)d_in[9];
  const float* mb2 = (const float*)d_in[10];

  float* out = (float*)d_out;                 // [32][1024]
  float* n1  = out + 32 * 1024;               // [2048][1024]
  float* n2  = n1 + 2048 * 1024;              // [2048][2048]
  float* n3  = n2 + 2048 * 2048;              // [1024][2048]
  float* P   = n3;                            // partials: n3 is dead until meta3 (K7)

  float* ws  = (float*)d_ws;
  float* xT  = ws;                            // 1024*32
  float* a1T = ws + 32768;                    // 2048*32
  float* a2T = a1T + 65536;                   // 2048*32
  float* v1  = a2T + 65536;                   // 2048
  float* v2  = v1 + 2048;                     // 2048

  // K0: x^T
  transp_x<<<16, NT, 0, stream>>>(x, xT);
  // K1: gemm1 (K=1024, O=2048, nto=32, KS=8, 32 slices of KLW=32)
  gemm_meta<32, 5><<<256, NT, 0, stream>>>(256, xT, w1, P, 1024, 2048,
      0, w1, w2, w3, x, v1, v2, out, n1, n2, n3, mw1, mb1, mw2, mb2);
  // K2: reduce1 -> a1T + v1
  reduceT<32, 5><<<256, NT, 0, stream>>>(P, b1, a1T, v1, 2048);
  // K3: gemm2 (K=2048, O=2048, nto=32, 32 slices of KLW=64) || meta layer-1
  gemm_meta<64, 5><<<256 + 1024, NT, 0, stream>>>(256, a1T, w2, P, 2048, 2048,
      0, w1, w2, w3, x, v1, v2, out, n1, n2, n3, mw1, mb1, mw2, mb2);
  // K4: reduce2 -> a2T + v2
  reduceT<32, 5><<<256, NT, 0, stream>>>(P, b2, a2T, v2, 2048);
  // K5: gemm3 (K=2048, O=1024, nto=16, 64 slices of KLW=32) || meta layer-2
  gemm_meta<32, 4><<<256 + 2048, NT, 0, stream>>>(256, a2T, w3, P, 2048, 1024,
      262144, w1, w2, w3, x, v1, v2, out, n1, n2, n3, mw1, mb1, mw2, mb2);
  // K6: reduce3 -> out (b-major)
  reduceOut<64><<<128, NT, 0, stream>>>(P, b3, out, 1024);
  // K7: meta layer-3 (reads out row 0; overwrites n3/P)
  meta_only<<<1024, NT, 0, stream>>>(786432, w1, w2, w3, x, v1, v2, out,
                                     n1, n2, n3, mw1, mb1, mw2, mb2);
}

// Round 6
// 75.708 us; speedup vs baseline: 1.0701x; 1.0701x over previous
//
#include <hip/hip_runtime.h>

#define NT 128

typedef float f2 __attribute__((ext_vector_type(2)));

// ================= meta body =================
// nw[o,i] = mb2 + sum_j mw2[j]*relu(mw1[3j]*vin[i] + mw1[3j+1]*W[o,i] + mw1[3j+2]*vout[o] + mb1[j])
__device__ __forceinline__ void meta_body(
    int g,
    const float* __restrict__ w1, const float* __restrict__ w2, const float* __restrict__ w3,
    const float* __restrict__ a0, const float* __restrict__ a1, const float* __restrict__ a2,
    const float* __restrict__ a3,
    float* __restrict__ n1, float* __restrict__ n2, float* __restrict__ n3,
    const float* __restrict__ mw1, const float* __restrict__ mb1,
    const float* __restrict__ mw2, const float* __restrict__ mb2) {
  const int n1c = (2048 * 1024) / 8;
  const int n2c = (2048 * 2048) / 8;

  const float* W; const float* vin; const float* vout; float* nw;
  int sh, e;
  if (g < n1c)            { W = w1; vin = a0; vout = a1; nw = n1; sh = 10; e = g; }
  else if (g < n1c + n2c) { W = w2; vin = a1; vout = a2; nw = n2; sh = 11; e = g - n1c; }
  else                    { W = w3; vin = a2; vout = a3; nw = n3; sh = 11; e = g - n1c - n2c; }

  const int base = e << 3;
  const int o = base >> sh;
  const int i0 = base & ((1 << sh) - 1);

  f2 wv[4], vv[4];
  {
    float4 t0 = *reinterpret_cast<const float4*>(&W[base]);
    float4 t1 = *reinterpret_cast<const float4*>(&W[base + 4]);
    wv[0] = (f2){t0.x, t0.y}; wv[1] = (f2){t0.z, t0.w};
    wv[2] = (f2){t1.x, t1.y}; wv[3] = (f2){t1.z, t1.w};
    float4 u0 = *reinterpret_cast<const float4*>(&vin[i0]);
    float4 u1 = *reinterpret_cast<const float4*>(&vin[i0 + 4]);
    vv[0] = (f2){u0.x, u0.y}; vv[1] = (f2){u0.z, u0.w};
    vv[2] = (f2){u1.x, u1.y}; vv[3] = (f2){u1.z, u1.w};
  }
  const float vo = vout[o];
  const float c2 = mb2[0];

  float r[32];
  #pragma unroll
  for (int j = 0; j < 32; ++j)
    r[j] = fmaf(mw1[3 * j + 2], vo, mb1[j]);

  f2 acc[4];
  #pragma unroll
  for (int p = 0; p < 4; ++p) acc[p] = (f2){c2, c2};

  const f2 zero = (f2){0.f, 0.f};
  #pragma unroll
  for (int j = 0; j < 32; ++j) {
    const float aj = mw1[3 * j];
    const float bj = mw1[3 * j + 1];
    const float mj = mw2[j];
    const f2 a2v = (f2){aj, aj};
    const f2 b2v = (f2){bj, bj};
    const f2 m2v = (f2){mj, mj};
    const f2 r2v = (f2){r[j], r[j]};
    #pragma unroll
    for (int p = 0; p < 4; ++p) {
#if __has_builtin(__builtin_elementwise_fma) && __has_builtin(__builtin_elementwise_max)
      f2 q = __builtin_elementwise_fma(a2v, vv[p], r2v);
      f2 h = __builtin_elementwise_fma(b2v, wv[p], q);
      h = __builtin_elementwise_max(h, zero);
      acc[p] = __builtin_elementwise_fma(m2v, h, acc[p]);
#else
      f2 h;
      h.x = fmaxf(fmaf(bj, wv[p].x, fmaf(aj, vv[p].x, r[j])), 0.f);
      h.y = fmaxf(fmaf(bj, wv[p].y, fmaf(aj, vv[p].y, r[j])), 0.f);
      acc[p].x = fmaf(mj, h.x, acc[p].x);
      acc[p].y = fmaf(mj, h.y, acc[p].y);
#endif
    }
  }

  *reinterpret_cast<float4*>(&nw[base])     = make_float4(acc[0].x, acc[0].y, acc[1].x, acc[1].y);
  *reinterpret_cast<float4*>(&nw[base + 4]) = make_float4(acc[2].x, acc[2].y, acc[3].x, acc[3].y);
}

// ================= gemm body =================
// Block tile 32b x 256o, thread tile 8b x 8o, 128 threads.
// Split-K: 32 slices; slice s = bid >> OTbits, otile = bid & mask.
// A [32][GK] b-major; W [O][GK]; P[s*32+b][o] (GO-contig).
__device__ __forceinline__ void gemm_body(
    int bid, int tid,
    const float* __restrict__ GA, const float* __restrict__ GW,
    float* __restrict__ GP, int GK, int OTbits, int KLB, int GO,
    float* __restrict__ Wt, float* __restrict__ At) {
  const int otile = bid & ((1 << OTbits) - 1);
  const int s = bid >> OTbits;
  const int obase = otile << 8;
  const int kbeg = s * KLB;
  const int to = tid & 31;   // o = obase + to + 32*i
  const int tb = tid >> 5;   // b = tb*8 + j

  float acc[8][8];
  #pragma unroll
  for (int j = 0; j < 8; ++j)
    #pragma unroll
    for (int i = 0; i < 8; ++i) acc[j][i] = 0.f;

  const int nch = KLB >> 5;
  for (int c = 0; c < nch; ++c) {
    const int kc = kbeg + (c << 5);
    // stage W [256][32], slot-swizzled: slot = p ^ (r & 7)
    #pragma unroll
    for (int t = 0; t < 16; ++t) {
      const int id = tid + (t << 7);       // 0..2047
      const int r = id >> 3, p = id & 7;
      const float4 v = *reinterpret_cast<const float4*>(
          &GW[(size_t)(obase + r) * GK + kc + (p << 2)]);
      *reinterpret_cast<float4*>(&Wt[(r << 5) + ((p ^ (r & 7)) << 2)]) = v;
    }
    // stage A [32][32], slot-swizzled: slot = p ^ ((r>>3)&3)
    #pragma unroll
    for (int t = 0; t < 2; ++t) {
      const int id = tid + (t << 7);       // 0..255
      const int r = id >> 3, p = id & 7;
      const float4 v = *reinterpret_cast<const float4*>(
          &GA[(size_t)r * GK + kc + (p << 2)]);
      *reinterpret_cast<float4*>(&At[(r << 5) + ((p ^ ((r >> 3) & 3)) << 2)]) = v;
    }
    __syncthreads();

    #pragma unroll
    for (int gq = 0; gq < 8; ++gq) {
      float4 av[8], wv[8];
      #pragma unroll
      for (int j = 0; j < 8; ++j)
        av[j] = *reinterpret_cast<const float4*>(
            &At[((tb * 8 + j) << 5) + ((gq ^ tb) << 2)]);
      const int wslot = (gq ^ (to & 7)) << 2;
      #pragma unroll
      for (int i = 0; i < 8; ++i)
        wv[i] = *reinterpret_cast<const float4*>(
            &Wt[((to + (i << 5)) << 5) + wslot]);
      #pragma unroll
      for (int j = 0; j < 8; ++j)
        #pragma unroll
        for (int i = 0; i < 8; ++i) {
          acc[j][i] = fmaf(av[j].x, wv[i].x, acc[j][i]);
          acc[j][i] = fmaf(av[j].y, wv[i].y, acc[j][i]);
          acc[j][i] = fmaf(av[j].z, wv[i].z, acc[j][i]);
          acc[j][i] = fmaf(av[j].w, wv[i].w, acc[j][i]);
        }
    }
    __syncthreads();
  }

  float* pb = GP + (size_t)(s * 32) * GO + obase + to;
  #pragma unroll
  for (int j = 0; j < 8; ++j) {
    float* pr = pb + (size_t)(tb * 8 + j) * GO;
    #pragma unroll
    for (int i = 0; i < 8; ++i)
      pr[i << 5] = acc[j][i];
  }
}

// ================= gemv body: row-0 activation chain =================
// wave-per-4-outputs: vR[o] = relu(sum_k vW[o][k]*vX[k] + vB[o])
__device__ __forceinline__ void gemv_body(
    int lbid, int tid,
    const float* __restrict__ vX, const float* __restrict__ vW,
    const float* __restrict__ vB, float* __restrict__ vR, int vK) {
  const int w = tid >> 6, l = tid & 63;
  const int obase = lbid * 8 + w * 4;
  const int nt = vK >> 8;                 // f4 chunks per lane (4 or 8)
  float4 xv[8];
  #pragma unroll 8
  for (int t = 0; t < nt; ++t)
    xv[t] = *reinterpret_cast<const float4*>(&vX[(l + (t << 6)) << 2]);
  #pragma unroll
  for (int q = 0; q < 4; ++q) {
    const int o = obase + q;
    const float* wr = vW + (size_t)o * vK;
    float a = 0.f;
    #pragma unroll 8
    for (int t = 0; t < nt; ++t) {
      const float4 wv = *reinterpret_cast<const float4*>(&wr[(l + (t << 6)) << 2]);
      a = fmaf(wv.x, xv[t].x, a); a = fmaf(wv.y, xv[t].y, a);
      a = fmaf(wv.z, xv[t].z, a); a = fmaf(wv.w, xv[t].w, a);
    }
    #pragma unroll
    for (int m = 32; m >= 1; m >>= 1)
      a += __shfl_xor(a, m, 64);
    if (l == 0) vR[o] = fmaxf(a + vB[o], 0.f);
  }
}

// ================= reduce body: sum 32 slices + bias + relu =================
__device__ __forceinline__ void red_body(
    int lbid, int tid, const float4* __restrict__ RP,
    const float* __restrict__ Rb, float* __restrict__ RC, int ROlog) {
  const int e4 = lbid * NT + tid;              // f4 index into [32][RO]
  const size_t sstride = (size_t)8 << ROlog;   // f4 per slice
  float4 s = RP[e4];
  #pragma unroll
  for (int sl = 1; sl < 32; ++sl) {
    const float4 v = RP[sstride * sl + e4];
    s.x += v.x; s.y += v.y; s.z += v.z; s.w += v.w;
  }
  const int of = (e4 << 2) & ((1 << ROlog) - 1);
  s.x = fmaxf(s.x + Rb[of], 0.f);
  s.y = fmaxf(s.y + Rb[of + 1], 0.f);
  s.z = fmaxf(s.z + Rb[of + 2], 0.f);
  s.w = fmaxf(s.w + Rb[of + 3], 0.f);
  *reinterpret_cast<float4*>(&RC[(size_t)e4 << 2]) = s;
}

// ================= combined role kernel =================
template<int HG>
__global__ __launch_bounds__(NT) void combo(
    int nGemm, const float* GA, const float* GW, float* GP,
    int GK, int OTbits, int KLB, int GO,
    int nGemv, const float* vX, const float* vW, const float* vB, float* vR, int vK,
    int nRed, const float4* RP, const float* Rb, float* RC, int ROlog,
    int metaBase,
    const float* w1, const float* w2, const float* w3,
    const float* a0, const float* a1r, const float* a2r, const float* a3r,
    float* n1, float* n2, float* n3,
    const float* mw1, const float* mb1, const float* mw2, const float* mb2) {
  const int bid = blockIdx.x;
  const int tid = threadIdx.x;
  if constexpr (HG != 0) {
    if (bid < nGemm) {
      __shared__ float Wt[256 * 32];
      __shared__ float At[32 * 32];
      gemm_body(bid, tid, GA, GW, GP, GK, OTbits, KLB, GO, Wt, At);
      return;
    }
  }
  int b = bid - nGemm;
  if (b < nGemv) { gemv_body(b, tid, vX, vW, vB, vR, vK); return; }
  b -= nGemv;
  if (b < nRed) { red_body(b, tid, RP, Rb, RC, ROlog); return; }
  b -= nRed;
  const int g = metaBase + b * NT + tid;
  meta_body(g, w1, w2, w3, a0, a1r, a2r, a3r, n1, n2, n3, mw1, mb1, mw2, mb2);
}

extern "C" void kernel_launch(void* const* d_in, const int* in_sizes, int n_in,
                              void* d_out, int out_size, void* d_ws, size_t ws_size,
                              hipStream_t stream) {
  const float* x   = (const float*)d_in[0];
  const float* w1  = (const float*)d_in[1];
  const float* b1  = (const float*)d_in[2];
  const float* w2  = (const float*)d_in[3];
  const float* b2  = (const float*)d_in[4];
  const float* w3  = (const float*)d_in[5];
  const float* b3  = (const float*)d_in[6];
  const float* mw1 = (const float*)d_in[7];
  const float* mb1 = (const float*)d_in[8];
  const float* mw2 = (const float*)d_in[9];
  const float* mb2 = (const float*)d_in[10];

  float* out = (float*)d_out;                 // [32][1024]
  float* n1  = out + 32 * 1024;               // [2048][1024]
  float* n2  = n1 + 2048 * 1024;              // [2048][2048]
  float* n3  = n2 + 2048 * 2048;              // [1024][2048]

  float* ws     = (float*)d_ws;
  float* a1row  = ws;                         // 2048
  float* a2row  = ws + 2048;                  // 2048
  float* outrow = ws + 4096;                  // 1024
  float* a1     = ws + 8192;                  // 32*2048
  float* a2     = a1 + 65536;                 // 32*2048
  float* P      = a2 + 65536;                 // 32*32*2048 = 2M floats (8 MB), reused 3x

  #define METAARGS w1, w2, w3, x, a1row, a2row, outrow, n1, n2, n3, mw1, mb1, mw2, mb2

  // K1: gemm1 (256 blk: x@w1 -> P) + gemv1 (256 blk: a1row)
  combo<1><<<512, NT, 0, stream>>>(
      256, x, w1, P, 1024, 3, 32, 2048,
      256, x, w1, b1, a1row, 1024,
      0, nullptr, nullptr, nullptr, 0,
      0, METAARGS);
  // K2: reduce1 (128: P->a1) + gemv2 (256: a2row) + meta [0, 262144)
  combo<0><<<2432, NT, 0, stream>>>(
      0, nullptr, nullptr, nullptr, 0, 0, 0, 0,
      256, a1row, w2, b2, a2row, 2048,
      128, (const float4*)P, b1, a1, 11,
      0, METAARGS);
  // K3: gemm2 (256: a1@w2 -> P) + gemv3 (128: outrow) + meta [262144, 524288)
  combo<1><<<2432, NT, 0, stream>>>(
      256, a1, w2, P, 2048, 3, 64, 2048,
      128, a2row, w3, b3, outrow, 2048,
      0, nullptr, nullptr, nullptr, 0,
      262144, METAARGS);
  // K4: reduce2 (128: P->a2) + meta [524288, 786432)
  combo<0><<<2176, NT, 0, stream>>>(
      0, nullptr, nullptr, nullptr, 0, 0, 0, 0,
      0, nullptr, nullptr, nullptr, nullptr, 0,
      128, (const float4*)P, b2, a2, 11,
      524288, METAARGS);
  // K5: gemm3 (128: a2@w3 -> P) + meta [786432, 983040)
  combo<1><<<1664, NT, 0, stream>>>(
      128, a2, w3, P, 2048, 2, 64, 1024,
      0, nullptr, nullptr, nullptr, nullptr, 0,
      0, nullptr, nullptr, nullptr, 0,
      786432, METAARGS);
  // K6: reduce3 (64: P->out) + meta [983040, 1048576)
  combo<0><<<576, NT, 0, stream>>>(
      0, nullptr, nullptr, nullptr, 0, 0, 0, 0,
      0, nullptr, nullptr, nullptr, nullptr, 0,
      64, (const float4*)P, b3, out, 10,
      983040, METAARGS);

  #undef METAARGS
}